// Round 1
// baseline (210.549 us; speedup 1.0000x reference)
//
#include <hip/hip_runtime.h>
#include <hip/hip_bf16.h>
#include <stdint.h>

#define NTOK 4096
#define DIM  1024

typedef unsigned short u16;
typedef __bf16 bf16x8 __attribute__((ext_vector_type(8)));
typedef float f32x4 __attribute__((ext_vector_type(4)));
typedef u16 u16x8 __attribute__((ext_vector_type(8)));

// ---------- helpers ----------
__device__ __forceinline__ u16 f2bf(float f) {
  union { float f; uint32_t u; } c; c.f = f;
  return (u16)((c.u + 0x7fffu + ((c.u >> 16) & 1u)) >> 16);  // RNE
}

__device__ __forceinline__ float wave_max(float v) {
#pragma unroll
  for (int o = 32; o; o >>= 1) v = fmaxf(v, __shfl_xor(v, o, 64));
  return v;
}
__device__ __forceinline__ float wave_sum(float v) {
#pragma unroll
  for (int o = 32; o; o >>= 1) v += __shfl_xor(v, o, 64);
  return v;
}

// ---------- fp32 -> bf16 conversion (vectorized, n % 1024 == 0) ----------
__global__ __launch_bounds__(256) void cvt_f32_bf16(const float* __restrict__ in,
                                                    u16* __restrict__ out) {
  int i = (blockIdx.x * 256 + threadIdx.x) * 4;
  float4 v = *reinterpret_cast<const float4*>(in + i);
  ushort4 o;
  o.x = f2bf(v.x); o.y = f2bf(v.y); o.z = f2bf(v.z); o.w = f2bf(v.w);
  *reinterpret_cast<ushort4*>(out + i) = o;
}

// ---------- generic C = A @ B^T,  A:[M,K] bf16, B:[N,K] bf16 (row-major) ----------
// 128x128 tile, BK=32, 256 threads = 4 waves (2x2), each wave 64x64 via 4x4 x mfma 16x16x32.
// EPI: 0 = bf16 out [M,N]; 1 = bf16 out transposed [N,M]; 2 = f32 out [M,N] * scale
// KLIMIT: stop K loop at row0+128 (causal PV);  CSKIP: skip blocks with bx > by (causal QK^T)
template<int EPI, bool KLIMIT, bool CSKIP>
__global__ __launch_bounds__(256) void gemm_bt(
    const u16* __restrict__ A, const u16* __restrict__ B, void* __restrict__ Cv,
    int M, int N, int K, int lda, int ldb, float scale)
{
  constexpr int BM = 128, BN = 128, BK = 32;
  constexpr int LDSS = BK + 8;  // +8 bf16 (16B) pad: breaks 64B-row bank aliasing, keeps 16B align
  __shared__ alignas(16) u16 sA[BM * LDSS];
  __shared__ alignas(16) u16 sB[BN * LDSS];
  const int bx = blockIdx.x, by = blockIdx.y;
  if (CSKIP && bx > by) return;
  const int tid  = threadIdx.x;
  const int wave = tid >> 6, lane = tid & 63;
  const int wr = wave >> 1, wc = wave & 1;
  const int l15 = lane & 15, l4 = lane >> 4;
  const int row0 = by * BM, col0 = bx * BN;
  const int Klim = KLIMIT ? ((row0 + BM < K) ? (row0 + BM) : K) : K;

  // staging: thread owns two 16B chunks (rows rs and rs+64, col chunk cs)
  const int rs = tid >> 2;
  const int cs = (tid & 3) * 8;
  const u16* gA0 = A + (size_t)(row0 + rs) * lda + cs;
  const u16* gA1 = gA0 + (size_t)64 * lda;
  const u16* gB0 = B + (size_t)(col0 + rs) * ldb + cs;
  const u16* gB1 = gB0 + (size_t)64 * ldb;
  u16* wA0 = &sA[rs * LDSS + cs];
  u16* wA1 = &sA[(rs + 64) * LDSS + cs];
  u16* wB0 = &sB[rs * LDSS + cs];
  u16* wB1 = &sB[(rs + 64) * LDSS + cs];

  f32x4 acc[4][4] = {};

  // prefetch k0 = 0
  u16x8 a0 = *reinterpret_cast<const u16x8*>(gA0);
  u16x8 a1 = *reinterpret_cast<const u16x8*>(gA1);
  u16x8 b0 = *reinterpret_cast<const u16x8*>(gB0);
  u16x8 b1 = *reinterpret_cast<const u16x8*>(gB1);

  for (int k0 = 0; k0 < Klim; k0 += BK) {
    __syncthreads();
    *reinterpret_cast<u16x8*>(wA0) = a0;
    *reinterpret_cast<u16x8*>(wA1) = a1;
    *reinterpret_cast<u16x8*>(wB0) = b0;
    *reinterpret_cast<u16x8*>(wB1) = b1;
    __syncthreads();
    if (k0 + BK < Klim) {  // issue next-tile global loads early; overlap with MFMA below
      a0 = *reinterpret_cast<const u16x8*>(gA0 + k0 + BK);
      a1 = *reinterpret_cast<const u16x8*>(gA1 + k0 + BK);
      b0 = *reinterpret_cast<const u16x8*>(gB0 + k0 + BK);
      b1 = *reinterpret_cast<const u16x8*>(gB1 + k0 + BK);
    }
    bf16x8 af[4], bfv[4];
#pragma unroll
    for (int mf = 0; mf < 4; ++mf)
      af[mf] = *reinterpret_cast<const bf16x8*>(&sA[(wr * 64 + mf * 16 + l15) * LDSS + l4 * 8]);
#pragma unroll
    for (int nf = 0; nf < 4; ++nf)
      bfv[nf] = *reinterpret_cast<const bf16x8*>(&sB[(wc * 64 + nf * 16 + l15) * LDSS + l4 * 8]);
#pragma unroll
    for (int mf = 0; mf < 4; ++mf)
#pragma unroll
      for (int nf = 0; nf < 4; ++nf)
        acc[mf][nf] = __builtin_amdgcn_mfma_f32_16x16x32_bf16(af[mf], bfv[nf], acc[mf][nf], 0, 0, 0);
  }

  // epilogue: C/D frag layout (16x16x32): col = lane&15, row = (lane>>4)*4 + r  [m89-verified]
  const int om = row0 + wr * 64;
  const int on = col0 + wc * 64;
  if constexpr (EPI == 0) {
    u16* C = (u16*)Cv;
#pragma unroll
    for (int mf = 0; mf < 4; ++mf)
#pragma unroll
      for (int nf = 0; nf < 4; ++nf)
#pragma unroll
        for (int r = 0; r < 4; ++r)
          C[(size_t)(om + mf * 16 + l4 * 4 + r) * N + (on + nf * 16 + l15)] = f2bf(acc[mf][nf][r]);
  } else if constexpr (EPI == 1) {
    u16* C = (u16*)Cv;  // [N][M]: transposed store, 4 consecutive rows -> contiguous 8B
#pragma unroll
    for (int mf = 0; mf < 4; ++mf)
#pragma unroll
      for (int nf = 0; nf < 4; ++nf) {
        ushort4 o;
        o.x = f2bf(acc[mf][nf][0]);
        o.y = f2bf(acc[mf][nf][1]);
        o.z = f2bf(acc[mf][nf][2]);
        o.w = f2bf(acc[mf][nf][3]);
        *reinterpret_cast<ushort4*>(&C[(size_t)(on + nf * 16 + l15) * M + (om + mf * 16 + l4 * 4)]) = o;
      }
  } else {
    float* C = (float*)Cv;
#pragma unroll
    for (int mf = 0; mf < 4; ++mf)
#pragma unroll
      for (int nf = 0; nf < 4; ++nf)
#pragma unroll
        for (int r = 0; r < 4; ++r)
          C[(size_t)(om + mf * 16 + l4 * 4 + r) * N + (on + nf * 16 + l15)] = acc[mf][nf][r] * scale;
  }
}

// ---------- causal row softmax: S fp32 [4096,4096] -> P bf16 [4096,4096] ----------
// one block per row; valid cols [0, row]; P[row][j>row] = 0 exactly.
__global__ __launch_bounds__(256) void softmax_causal(const float* __restrict__ S,
                                                      u16* __restrict__ P) {
  __shared__ float buf[NTOK];
  __shared__ float red[8];
  const int row = blockIdx.x;
  const int tid = threadIdx.x;
  const int limit = row + 1;
  const float* srow = S + (size_t)row * NTOK;

  float lmax = -1e30f;
  for (int j = tid * 4; j < NTOK; j += 1024) {
    float4 s;
    if (j + 4 <= limit) {
      s = *reinterpret_cast<const float4*>(srow + j);
    } else {
      s.x = (j + 0 < limit) ? srow[j + 0] : -1e30f;
      s.y = (j + 1 < limit) ? srow[j + 1] : -1e30f;
      s.z = (j + 2 < limit) ? srow[j + 2] : -1e30f;
      s.w = (j + 3 < limit) ? srow[j + 3] : -1e30f;
    }
    *reinterpret_cast<float4*>(buf + j) = s;
    lmax = fmaxf(lmax, fmaxf(fmaxf(s.x, s.y), fmaxf(s.z, s.w)));
  }
  lmax = wave_max(lmax);
  if ((tid & 63) == 0) red[tid >> 6] = lmax;
  __syncthreads();
  const float m = fmaxf(fmaxf(red[0], red[1]), fmaxf(red[2], red[3]));

  float lsum = 0.f;
  for (int j = tid * 4; j < NTOK; j += 1024) {
    float4 s = *reinterpret_cast<float4*>(buf + j);
    float4 e;
    e.x = __expf(s.x - m); e.y = __expf(s.y - m);
    e.z = __expf(s.z - m); e.w = __expf(s.w - m);
    *reinterpret_cast<float4*>(buf + j) = e;
    lsum += (e.x + e.y) + (e.z + e.w);
  }
  lsum = wave_sum(lsum);
  if ((tid & 63) == 0) red[4 + (tid >> 6)] = lsum;
  __syncthreads();
  const float inv = 1.0f / (red[4] + red[5] + red[6] + red[7]);

  u16* prow = P + (size_t)row * NTOK;
  for (int j = tid * 4; j < NTOK; j += 1024) {
    float4 e = *reinterpret_cast<float4*>(buf + j);
    ushort4 o;
    o.x = f2bf(e.x * inv); o.y = f2bf(e.y * inv);
    o.z = f2bf(e.z * inv); o.w = f2bf(e.w * inv);
    *reinterpret_cast<ushort4*>(prow + j) = o;
  }
}

// ---------- launcher ----------
extern "C" void kernel_launch(void* const* d_in, const int* in_sizes, int n_in,
                              void* d_out, int out_size, void* d_ws, size_t ws_size,
                              hipStream_t stream) {
  const float* qx = (const float*)d_in[0];
  const float* kx = (const float*)d_in[1];
  const float* vx = (const float*)d_in[2];
  const float* Wq = (const float*)d_in[3];
  const float* Wk = (const float*)d_in[4];
  const float* Wv = (const float*)d_in[5];
  float* out = (float*)d_out;
  char* ws = (char*)d_ws;
  const size_t MB = 1024ull * 1024ull;

  if (ws_size < 120 * MB) {
    // loudly signal insufficient workspace (NaN output, distinguishable from stub's zeros)
    hipMemsetAsync(d_out, 0xFF, (size_t)out_size * sizeof(float), stream);
    return;
  }

  // layout (120 MB): S fp32 [0,64MB) overlays the cvt buffers (dead before S is written)
  float* S  = (float*)(ws);
  u16* qxb  = (u16*)(ws);            // 8MB
  u16* kxb  = (u16*)(ws + 8 * MB);   // 8MB
  u16* vxb  = (u16*)(ws + 16 * MB);  // 8MB
  u16* Wqb  = (u16*)(ws + 24 * MB);  // 2MB
  u16* Wkb  = (u16*)(ws + 26 * MB);  // 2MB
  u16* Wvb  = (u16*)(ws + 28 * MB);  // 2MB
  u16* qb   = (u16*)(ws + 64 * MB);  // 8MB  q bf16 [4096,1024]
  u16* kb   = (u16*)(ws + 72 * MB);  // 8MB  k bf16 [4096,1024]
  u16* vTb  = (u16*)(ws + 80 * MB);  // 8MB  v^T bf16 [1024,4096]
  u16* P    = (u16*)(ws + 88 * MB);  // 32MB P bf16 [4096,4096]

  cvt_f32_bf16<<<4096, 256, 0, stream>>>(qx, qxb);
  cvt_f32_bf16<<<4096, 256, 0, stream>>>(kx, kxb);
  cvt_f32_bf16<<<4096, 256, 0, stream>>>(vx, vxb);
  cvt_f32_bf16<<<1024, 256, 0, stream>>>(Wq, Wqb);
  cvt_f32_bf16<<<1024, 256, 0, stream>>>(Wk, Wkb);
  cvt_f32_bf16<<<1024, 256, 0, stream>>>(Wv, Wvb);

  // projections: y = x @ W^T  (BT layout is native). v is stored transposed for the PV GEMM.
  dim3 gp(DIM / 128, NTOK / 128);
  gemm_bt<0, false, false><<<gp, 256, 0, stream>>>(qxb, Wqb, qb,  NTOK, DIM, DIM, DIM, DIM, 1.0f);
  gemm_bt<0, false, false><<<gp, 256, 0, stream>>>(kxb, Wkb, kb,  NTOK, DIM, DIM, DIM, DIM, 1.0f);
  gemm_bt<1, false, false><<<gp, 256, 0, stream>>>(vxb, Wvb, vTb, NTOK, DIM, DIM, DIM, DIM, 1.0f);

  // scores: S = (q @ k^T) / 32, lower-triangular tiles only (mask applied by softmax)
  dim3 gs(NTOK / 128, NTOK / 128);
  gemm_bt<2, false, true><<<gs, 256, 0, stream>>>(qb, kb, S, NTOK, NTOK, DIM, DIM, DIM, 0.03125f);

  softmax_causal<<<NTOK, 256, 0, stream>>>(S, P);

  // out = P @ v = P @ (v^T)^T, K limited to row0+128 (P is exactly 0 beyond the diagonal)
  dim3 go(DIM / 128, NTOK / 128);
  gemm_bt<2, true, false><<<go, 256, 0, stream>>>(P, vTb, out, NTOK, DIM, NTOK, NTOK, NTOK, 1.0f);
}

// Round 2
// 177.828 us; speedup vs baseline: 1.1840x; 1.1840x over previous
//
#include <hip/hip_runtime.h>
#include <hip/hip_bf16.h>
#include <stdint.h>

#define NTOK 4096
#define DIM  1024

typedef unsigned short u16;
typedef __bf16 bf16x8 __attribute__((ext_vector_type(8)));
typedef float f32x4 __attribute__((ext_vector_type(4)));
typedef u16 u16x8 __attribute__((ext_vector_type(8)));

// ---------- helpers ----------
__device__ __forceinline__ u16 f2bf(float f) {
  union { float f; uint32_t u; } c; c.f = f;
  return (u16)((c.u + 0x7fffu + ((c.u >> 16) & 1u)) >> 16);  // RNE
}

__device__ __forceinline__ u16x8 cvt8(float4 a, float4 b) {
  u16x8 r;
  r[0] = f2bf(a.x); r[1] = f2bf(a.y); r[2] = f2bf(a.z); r[3] = f2bf(a.w);
  r[4] = f2bf(b.x); r[5] = f2bf(b.y); r[6] = f2bf(b.z); r[7] = f2bf(b.w);
  return r;
}

__device__ __forceinline__ float wave_max(float v) {
#pragma unroll
  for (int o = 32; o; o >>= 1) v = fmaxf(v, __shfl_xor(v, o, 64));
  return v;
}
__device__ __forceinline__ float wave_sum(float v) {
#pragma unroll
  for (int o = 32; o; o >>= 1) v += __shfl_xor(v, o, 64);
  return v;
}

// async global->LDS, 16B per lane. LDS dest must be wave-uniform base (HW adds lane*16).
__device__ __forceinline__ void gld16(const u16* g, u16* l) {
  __builtin_amdgcn_global_load_lds((const __attribute__((address_space(1))) void*)g,
                                   (__attribute__((address_space(3))) void*)l, 16, 0, 0);
}

// ============================================================================
// Fused projections: q = qx@Wq^T, k = kx@Wk^T, v^T (z selects). fp32 in, bf16 out.
// 128x128x32 tile, reg-staged (fp32->bf16 convert inline), padded LDS.
// grid (DIM/128, NTOK/128, 3) = 768 blocks.
// ============================================================================
__global__ __launch_bounds__(256) void proj_gemm(
    const float* __restrict__ qx, const float* __restrict__ kx, const float* __restrict__ vx,
    const float* __restrict__ Wq, const float* __restrict__ Wk, const float* __restrict__ Wv,
    u16* __restrict__ qb, u16* __restrict__ kb, u16* __restrict__ vT)
{
  constexpr int BK = 32, LDSS = 40;  // +8 u16 pad (16B): breaks row-stride bank aliasing
  __shared__ alignas(16) u16 sA[128 * LDSS];
  __shared__ alignas(16) u16 sB[128 * LDSS];
  const int z = blockIdx.z;
  const float* A = (z == 0) ? qx : (z == 1) ? kx : vx;
  const float* B = (z == 0) ? Wq : (z == 1) ? Wk : Wv;
  const int bx = blockIdx.x, by = blockIdx.y;
  const int tid = threadIdx.x;
  const int wave = tid >> 6, lane = tid & 63;
  const int wr = wave >> 1, wc = wave & 1;
  const int l15 = lane & 15, l4 = lane >> 4;
  const int row0 = by * 128, col0 = bx * 128;

  const int rs = tid >> 2;
  const int cs = (tid & 3) * 8;
  const float* gA0 = A + (size_t)(row0 + rs) * DIM + cs;
  const float* gA1 = gA0 + (size_t)64 * DIM;
  const float* gB0 = B + (size_t)(col0 + rs) * DIM + cs;
  const float* gB1 = gB0 + (size_t)64 * DIM;
  u16* wA0 = &sA[rs * LDSS + cs];
  u16* wA1 = &sA[(rs + 64) * LDSS + cs];
  u16* wB0 = &sB[rs * LDSS + cs];
  u16* wB1 = &sB[(rs + 64) * LDSS + cs];

  f32x4 acc[4][4] = {};

  float4 a00 = *reinterpret_cast<const float4*>(gA0);
  float4 a01 = *reinterpret_cast<const float4*>(gA0 + 4);
  float4 a10 = *reinterpret_cast<const float4*>(gA1);
  float4 a11 = *reinterpret_cast<const float4*>(gA1 + 4);
  float4 b00 = *reinterpret_cast<const float4*>(gB0);
  float4 b01 = *reinterpret_cast<const float4*>(gB0 + 4);
  float4 b10 = *reinterpret_cast<const float4*>(gB1);
  float4 b11 = *reinterpret_cast<const float4*>(gB1 + 4);

  for (int k0 = 0; k0 < DIM; k0 += BK) {
    __syncthreads();
    *reinterpret_cast<u16x8*>(wA0) = cvt8(a00, a01);
    *reinterpret_cast<u16x8*>(wA1) = cvt8(a10, a11);
    *reinterpret_cast<u16x8*>(wB0) = cvt8(b00, b01);
    *reinterpret_cast<u16x8*>(wB1) = cvt8(b10, b11);
    __syncthreads();
    if (k0 + BK < DIM) {
      a00 = *reinterpret_cast<const float4*>(gA0 + k0 + BK);
      a01 = *reinterpret_cast<const float4*>(gA0 + k0 + BK + 4);
      a10 = *reinterpret_cast<const float4*>(gA1 + k0 + BK);
      a11 = *reinterpret_cast<const float4*>(gA1 + k0 + BK + 4);
      b00 = *reinterpret_cast<const float4*>(gB0 + k0 + BK);
      b01 = *reinterpret_cast<const float4*>(gB0 + k0 + BK + 4);
      b10 = *reinterpret_cast<const float4*>(gB1 + k0 + BK);
      b11 = *reinterpret_cast<const float4*>(gB1 + k0 + BK + 4);
    }
    bf16x8 af[4], bfv[4];
#pragma unroll
    for (int mf = 0; mf < 4; ++mf)
      af[mf] = *reinterpret_cast<const bf16x8*>(&sA[(wr * 64 + mf * 16 + l15) * LDSS + l4 * 8]);
#pragma unroll
    for (int nf = 0; nf < 4; ++nf)
      bfv[nf] = *reinterpret_cast<const bf16x8*>(&sB[(wc * 64 + nf * 16 + l15) * LDSS + l4 * 8]);
#pragma unroll
    for (int mf = 0; mf < 4; ++mf)
#pragma unroll
      for (int nf = 0; nf < 4; ++nf)
        acc[mf][nf] = __builtin_amdgcn_mfma_f32_16x16x32_bf16(af[mf], bfv[nf], acc[mf][nf], 0, 0, 0);
  }

  const int om = row0 + wr * 64;
  const int on = col0 + wc * 64;
  if (z < 2) {  // q/k: bf16 [NTOK, DIM]
    u16* C = (z == 0) ? qb : kb;
#pragma unroll
    for (int mf = 0; mf < 4; ++mf)
#pragma unroll
      for (int nf = 0; nf < 4; ++nf)
#pragma unroll
        for (int r = 0; r < 4; ++r)
          C[(size_t)(om + mf * 16 + l4 * 4 + r) * DIM + (on + nf * 16 + l15)] = f2bf(acc[mf][nf][r]);
  } else {      // v: transposed bf16 [DIM, NTOK]
#pragma unroll
    for (int mf = 0; mf < 4; ++mf)
#pragma unroll
      for (int nf = 0; nf < 4; ++nf) {
        ushort4 o;
        o.x = f2bf(acc[mf][nf][0]);
        o.y = f2bf(acc[mf][nf][1]);
        o.z = f2bf(acc[mf][nf][2]);
        o.w = f2bf(acc[mf][nf][3]);
        *reinterpret_cast<ushort4*>(&vT[(size_t)(on + nf * 16 + l15) * NTOK + (om + mf * 16 + l4 * 4)]) = o;
      }
  }
}

// ============================================================================
// Swizzled global_load_lds GEMM: C = A @ B^T (both [rows, K] bf16), fp32 out.
// 128x128 tile, BK=64. LDS: linear dest for gload_lds; XOR-swizzle via
// pre-swizzled GLOBAL source (chunk = (lane&7)^(lane>>3)) + swizzled ds_read.
// MODE 0 = scores (skip bx>by, store *scale). MODE 1 = PV split-K:
//   rows<2048: single chunk, plain store; rows>=2048: K split in half, both
//   halves atomicAdd into pre-zeroed out (2 addends -> commutative -> deterministic).
// ============================================================================
template<int MODE>
__global__ __launch_bounds__(256) void gemm_sw(
    const u16* __restrict__ A, const u16* __restrict__ B, float* __restrict__ C,
    int lda, int ldb, int ldc, int K, float scale)
{
  __shared__ alignas(16) u16 sA[128 * 64];
  __shared__ alignas(16) u16 sB[128 * 64];
  const int bx = blockIdx.x, by = blockIdx.y;
  const int row0 = by * 128, col0 = bx * 128;
  int klo = 0, khi = K;
  bool use_atomic = false;
  if constexpr (MODE == 0) {
    if (bx > by) return;
  } else {
    const int Klim = row0 + 128;
    if (Klim <= 2048) {
      if (blockIdx.z) return;
      khi = Klim;
    } else {
      use_atomic = true;
      const int Kh = Klim >> 1;  // multiple of 64
      if (blockIdx.z == 0) { klo = 0; khi = Kh; } else { klo = Kh; khi = Klim; }
    }
  }
  const int tid = threadIdx.x;
  const int wave = tid >> 6, lane = tid & 63;
  const int wr = wave >> 1, wc = wave & 1;
  const int l15 = lane & 15, l4 = lane >> 4;
  const int h = l15 & 7;

  // staging: per wave 32 rows; lane l -> row +(l>>3), pre-swizzled chunk (l&7)^(l>>3)
  const int srow = wave * 32 + (lane >> 3);
  const int scol = ((lane & 7) ^ (lane >> 3)) << 3;
  const u16* gA = A + (size_t)(row0 + srow) * lda + scol;
  const u16* gB = B + (size_t)(col0 + srow) * ldb + scol;
  const int lbase = wave * 32 * 64;

  f32x4 acc[4][4] = {};

  for (int k0 = klo; k0 < khi; k0 += 64) {
    __syncthreads();
#pragma unroll
    for (int i = 0; i < 4; ++i) {
      gld16(gA + (size_t)(i * 8) * lda + k0, &sA[lbase + i * 8 * 64]);
      gld16(gB + (size_t)(i * 8) * ldb + k0, &sB[lbase + i * 8 * 64]);
    }
    __syncthreads();  // compiler drains vmcnt(0) before barrier -> LDS ready
#pragma unroll
    for (int ks = 0; ks < 2; ++ks) {
      bf16x8 af[4], bfv[4];
#pragma unroll
      for (int mf = 0; mf < 4; ++mf)
        af[mf] = *reinterpret_cast<const bf16x8*>(
            (const char*)sA + ((wr * 64 + mf * 16 + l15) << 7) + ((((ks << 2) + l4) ^ h) << 4));
#pragma unroll
      for (int nf = 0; nf < 4; ++nf)
        bfv[nf] = *reinterpret_cast<const bf16x8*>(
            (const char*)sB + ((wc * 64 + nf * 16 + l15) << 7) + ((((ks << 2) + l4) ^ h) << 4));
#pragma unroll
      for (int mf = 0; mf < 4; ++mf)
#pragma unroll
        for (int nf = 0; nf < 4; ++nf)
          acc[mf][nf] = __builtin_amdgcn_mfma_f32_16x16x32_bf16(af[mf], bfv[nf], acc[mf][nf], 0, 0, 0);
    }
  }

  const int om = row0 + wr * 64;
  const int on = col0 + wc * 64;
#pragma unroll
  for (int mf = 0; mf < 4; ++mf)
#pragma unroll
    for (int nf = 0; nf < 4; ++nf)
#pragma unroll
      for (int r = 0; r < 4; ++r) {
        const float v = acc[mf][nf][r] * scale;
        const size_t idx = (size_t)(om + mf * 16 + l4 * 4 + r) * ldc + (on + nf * 16 + l15);
        if (MODE == 1 && use_atomic) atomicAdd(&C[idx], v);
        else C[idx] = v;
      }
}

// ---------- causal row softmax: S fp32 -> P bf16, only cols < (row&~127)+128 ----------
__global__ __launch_bounds__(256) void softmax_causal(const float* __restrict__ S,
                                                      u16* __restrict__ P) {
  __shared__ float buf[NTOK];
  __shared__ float red[8];
  const int row = blockIdx.x;
  const int tid = threadIdx.x;
  const int limit = row + 1;
  const int limit128 = (row & ~127) + 128;  // same for all rows in a 128-block
  const float* srow = S + (size_t)row * NTOK;

  float lmax = -1e30f;
  for (int j = tid * 4; j < limit128; j += 1024) {
    float4 s;
    if (j + 4 <= limit) {
      s = *reinterpret_cast<const float4*>(srow + j);
    } else {
      s.x = (j + 0 < limit) ? srow[j + 0] : -1e30f;
      s.y = (j + 1 < limit) ? srow[j + 1] : -1e30f;
      s.z = (j + 2 < limit) ? srow[j + 2] : -1e30f;
      s.w = (j + 3 < limit) ? srow[j + 3] : -1e30f;
    }
    *reinterpret_cast<float4*>(buf + j) = s;
    lmax = fmaxf(lmax, fmaxf(fmaxf(s.x, s.y), fmaxf(s.z, s.w)));
  }
  lmax = wave_max(lmax);
  if ((tid & 63) == 0) red[tid >> 6] = lmax;
  __syncthreads();
  const float m = fmaxf(fmaxf(red[0], red[1]), fmaxf(red[2], red[3]));

  float lsum = 0.f;
  for (int j = tid * 4; j < limit128; j += 1024) {
    float4 s = *reinterpret_cast<float4*>(buf + j);
    float4 e;
    e.x = __expf(s.x - m); e.y = __expf(s.y - m);
    e.z = __expf(s.z - m); e.w = __expf(s.w - m);
    *reinterpret_cast<float4*>(buf + j) = e;
    lsum += (e.x + e.y) + (e.z + e.w);
  }
  lsum = wave_sum(lsum);
  if ((tid & 63) == 0) red[4 + (tid >> 6)] = lsum;
  __syncthreads();
  const float inv = 1.0f / (red[4] + red[5] + red[6] + red[7]);

  u16* prow = P + (size_t)row * NTOK;
  for (int j = tid * 4; j < limit128; j += 1024) {
    float4 e = *reinterpret_cast<float4*>(buf + j);
    ushort4 o;
    o.x = f2bf(e.x * inv); o.y = f2bf(e.y * inv);
    o.z = f2bf(e.z * inv); o.w = f2bf(e.w * inv);
    *reinterpret_cast<ushort4*>(prow + j) = o;
  }
}

// ---------- launcher ----------
extern "C" void kernel_launch(void* const* d_in, const int* in_sizes, int n_in,
                              void* d_out, int out_size, void* d_ws, size_t ws_size,
                              hipStream_t stream) {
  const float* qx = (const float*)d_in[0];
  const float* kx = (const float*)d_in[1];
  const float* vx = (const float*)d_in[2];
  const float* Wq = (const float*)d_in[3];
  const float* Wk = (const float*)d_in[4];
  const float* Wv = (const float*)d_in[5];
  float* out = (float*)d_out;
  char* ws = (char*)d_ws;
  const size_t MB = 1024ull * 1024ull;

  if (ws_size < 120 * MB) {
    hipMemsetAsync(d_out, 0xFF, (size_t)out_size * sizeof(float), stream);
    return;
  }

  // ws layout (120 MB): S fp32 [0,64) | qb [64,72) | kb [72,80) | vT [80,88) | P [88,120)
  float* S = (float*)(ws);
  u16* qb  = (u16*)(ws + 64 * MB);
  u16* kb  = (u16*)(ws + 72 * MB);
  u16* vT  = (u16*)(ws + 80 * MB);
  u16* P   = (u16*)(ws + 88 * MB);

  // zero rows >= 2048 of out (atomicAdd targets for the split-K PV)
  hipMemsetAsync((char*)out + (size_t)2048 * DIM * 4, 0, (size_t)2048 * DIM * 4, stream);

  // fused projections (cvt folded into staging), 768 blocks
  proj_gemm<<<dim3(DIM / 128, NTOK / 128, 3), 256, 0, stream>>>(qx, kx, vx, Wq, Wk, Wv, qb, kb, vT);

  // scores: S = (q @ k^T) / 32, lower-triangular tiles only
  gemm_sw<0><<<dim3(NTOK / 128, NTOK / 128), 256, 0, stream>>>(qb, kb, S, DIM, DIM, NTOK, DIM, 0.03125f);

  softmax_causal<<<NTOK, 256, 0, stream>>>(S, P);

  // out = P @ v, causal K-limit, split-K for rows >= 2048
  gemm_sw<1><<<dim3(DIM / 128, NTOK / 128, 2), 256, 0, stream>>>(P, vT, out, NTOK, NTOK, DIM, NTOK, 1.0f);
}

// Round 3
// 160.142 us; speedup vs baseline: 1.3148x; 1.1104x over previous
//
#include <hip/hip_runtime.h>
#include <hip/hip_bf16.h>
#include <stdint.h>

#define NTOK 4096
#define DIM  1024

typedef unsigned short u16;
typedef __bf16 bf16x8 __attribute__((ext_vector_type(8)));
typedef float f32x4 __attribute__((ext_vector_type(4)));
typedef u16 u16x8 __attribute__((ext_vector_type(8)));

// ---------- helpers ----------
__device__ __forceinline__ u16 f2bf(float f) {
  union { float f; uint32_t u; } c; c.f = f;
  return (u16)((c.u + 0x7fffu + ((c.u >> 16) & 1u)) >> 16);  // RNE
}

__device__ __forceinline__ float wave_max(float v) {
#pragma unroll
  for (int o = 32; o; o >>= 1) v = fmaxf(v, __shfl_xor(v, o, 64));
  return v;
}
__device__ __forceinline__ float wave_sum(float v) {
#pragma unroll
  for (int o = 32; o; o >>= 1) v += __shfl_xor(v, o, 64);
  return v;
}

// async global->LDS, 16B per lane. LDS dest must be wave-uniform base (HW adds lane*16).
__device__ __forceinline__ void gld16(const u16* g, u16* l) {
  __builtin_amdgcn_global_load_lds((const __attribute__((address_space(1))) void*)g,
                                   (__attribute__((address_space(3))) void*)l, 16, 0, 0);
}

// ============================================================================
// fp32 -> bf16 conversion, 8 elems/thread. z selects tensor; blocks beyond a
// tensor's size return early (x tensors need 2048 blocks, W tensors 512).
// ============================================================================
__global__ __launch_bounds__(256) void cvt6(
    const float* __restrict__ qx, const float* __restrict__ kx, const float* __restrict__ vx,
    const float* __restrict__ Wq, const float* __restrict__ Wk, const float* __restrict__ Wv,
    u16* __restrict__ qxb, u16* __restrict__ kxb, u16* __restrict__ vxb,
    u16* __restrict__ Wqb, u16* __restrict__ Wkb, u16* __restrict__ Wvb)
{
  const int z = blockIdx.z;
  const int nelem = (z < 3) ? NTOK * DIM : DIM * DIM;
  const int i = (blockIdx.x * 256 + threadIdx.x) * 8;
  if (i >= nelem) return;
  const float* in = (z == 0) ? qx : (z == 1) ? kx : (z == 2) ? vx
                  : (z == 3) ? Wq : (z == 4) ? Wk : Wv;
  u16* out = (z == 0) ? qxb : (z == 1) ? kxb : (z == 2) ? vxb
           : (z == 3) ? Wqb : (z == 4) ? Wkb : Wvb;
  float4 a = *reinterpret_cast<const float4*>(in + i);
  float4 b = *reinterpret_cast<const float4*>(in + i + 4);
  u16x8 o;
  o[0] = f2bf(a.x); o[1] = f2bf(a.y); o[2] = f2bf(a.z); o[3] = f2bf(a.w);
  o[4] = f2bf(b.x); o[5] = f2bf(b.y); o[6] = f2bf(b.z); o[7] = f2bf(b.w);
  *reinterpret_cast<u16x8*>(out + i) = o;
}

// ============================================================================
// Shared 128x128xK core: C128 = A @ B^T accumulate (A:[*,lda], B:[*,ldb] bf16).
// global_load_lds(16B) staging, linear LDS dest, pre-swizzled global source
// (chunk = (lane&7)^(lane>>3)), XOR-swizzled ds_read -> conflict-free.
// ============================================================================
__device__ __forceinline__ void mm128(
    const u16* __restrict__ A, const u16* __restrict__ B,
    int lda, int ldb, int klo, int khi, int row0, int col0,
    u16* sA, u16* sB, f32x4 (&acc)[4][4])
{
  const int tid = threadIdx.x;
  const int wave = tid >> 6, lane = tid & 63;
  const int wr = wave >> 1, wc = wave & 1;
  const int l15 = lane & 15, l4 = lane >> 4;
  const int h = l15 & 7;

  const int srow = wave * 32 + (lane >> 3);
  const int scol = ((lane & 7) ^ (lane >> 3)) << 3;
  const u16* gA = A + (size_t)(row0 + srow) * lda + scol;
  const u16* gB = B + (size_t)(col0 + srow) * ldb + scol;
  const int lbase = wave * 32 * 64;

  for (int k0 = klo; k0 < khi; k0 += 64) {
    __syncthreads();
#pragma unroll
    for (int i = 0; i < 4; ++i) {
      gld16(gA + (size_t)(i * 8) * lda + k0, &sA[lbase + i * 8 * 64]);
      gld16(gB + (size_t)(i * 8) * ldb + k0, &sB[lbase + i * 8 * 64]);
    }
    __syncthreads();  // compiler drains vmcnt(0) before barrier -> LDS ready
#pragma unroll
    for (int ks = 0; ks < 2; ++ks) {
      bf16x8 af[4], bfv[4];
#pragma unroll
      for (int mf = 0; mf < 4; ++mf)
        af[mf] = *reinterpret_cast<const bf16x8*>(
            (const char*)sA + ((wr * 64 + mf * 16 + l15) << 7) + ((((ks << 2) + l4) ^ h) << 4));
#pragma unroll
      for (int nf = 0; nf < 4; ++nf)
        bfv[nf] = *reinterpret_cast<const bf16x8*>(
            (const char*)sB + ((wc * 64 + nf * 16 + l15) << 7) + ((((ks << 2) + l4) ^ h) << 4));
#pragma unroll
      for (int mf = 0; mf < 4; ++mf)
#pragma unroll
        for (int nf = 0; nf < 4; ++nf)
          acc[mf][nf] = __builtin_amdgcn_mfma_f32_16x16x32_bf16(af[mf], bfv[nf], acc[mf][nf], 0, 0, 0);
    }
  }
}

// ============================================================================
// Projections: y = x @ W^T, bf16 in (pre-converted) / bf16 out. z selects.
// z=0: qb [NTOK,DIM]; z=1: kb; z=2: vT [DIM,NTOK] (transposed store for PV).
// grid (DIM/128, NTOK/128, 3) = 768 blocks = 3 blocks/CU.
// ============================================================================
__global__ __launch_bounds__(256) void proj_sw(
    const u16* __restrict__ qxb, const u16* __restrict__ kxb, const u16* __restrict__ vxb,
    const u16* __restrict__ Wqb, const u16* __restrict__ Wkb, const u16* __restrict__ Wvb,
    u16* __restrict__ qb, u16* __restrict__ kb, u16* __restrict__ vT)
{
  __shared__ alignas(16) u16 sA[128 * 64];
  __shared__ alignas(16) u16 sB[128 * 64];
  const int z = blockIdx.z;
  const u16* A = (z == 0) ? qxb : (z == 1) ? kxb : vxb;
  const u16* B = (z == 0) ? Wqb : (z == 1) ? Wkb : Wvb;
  const int row0 = blockIdx.y * 128, col0 = blockIdx.x * 128;

  f32x4 acc[4][4] = {};
  mm128(A, B, DIM, DIM, 0, DIM, row0, col0, sA, sB, acc);

  const int lane = threadIdx.x & 63;
  const int wave = threadIdx.x >> 6;
  const int l15 = lane & 15, l4 = lane >> 4;
  const int om = row0 + (wave >> 1) * 64;
  const int on = col0 + (wave & 1) * 64;
  if (z < 2) {
    u16* C = (z == 0) ? qb : kb;
#pragma unroll
    for (int mf = 0; mf < 4; ++mf)
#pragma unroll
      for (int nf = 0; nf < 4; ++nf)
#pragma unroll
        for (int r = 0; r < 4; ++r)
          C[(size_t)(om + mf * 16 + l4 * 4 + r) * DIM + (on + nf * 16 + l15)] = f2bf(acc[mf][nf][r]);
  } else {  // v transposed: 4 consecutive rows -> contiguous 8B store
#pragma unroll
    for (int mf = 0; mf < 4; ++mf)
#pragma unroll
      for (int nf = 0; nf < 4; ++nf) {
        ushort4 o;
        o.x = f2bf(acc[mf][nf][0]);
        o.y = f2bf(acc[mf][nf][1]);
        o.z = f2bf(acc[mf][nf][2]);
        o.w = f2bf(acc[mf][nf][3]);
        *reinterpret_cast<ushort4*>(&vT[(size_t)(on + nf * 16 + l15) * NTOK + (om + mf * 16 + l4 * 4)]) = o;
      }
  }
}

// ============================================================================
// Scores: S = (q @ k^T) * scale, lower-triangular tiles only. fp32 out.
// ============================================================================
__global__ __launch_bounds__(256) void gemm_scores(
    const u16* __restrict__ A, const u16* __restrict__ B, float* __restrict__ C, float scale)
{
  __shared__ alignas(16) u16 sA[128 * 64];
  __shared__ alignas(16) u16 sB[128 * 64];
  const int bx = blockIdx.x, by = blockIdx.y;
  if (bx > by) return;
  const int row0 = by * 128, col0 = bx * 128;

  f32x4 acc[4][4] = {};
  mm128(A, B, DIM, DIM, 0, DIM, row0, col0, sA, sB, acc);

  const int lane = threadIdx.x & 63;
  const int wave = threadIdx.x >> 6;
  const int l15 = lane & 15, l4 = lane >> 4;
  const int om = row0 + (wave >> 1) * 64;
  const int on = col0 + (wave & 1) * 64;
#pragma unroll
  for (int mf = 0; mf < 4; ++mf)
#pragma unroll
    for (int nf = 0; nf < 4; ++nf)
#pragma unroll
      for (int r = 0; r < 4; ++r)
        C[(size_t)(om + mf * 16 + l4 * 4 + r) * NTOK + (on + nf * 16 + l15)] = acc[mf][nf][r] * scale;
}

// ============================================================================
// PV: out = P @ vT^T, causal K-limit (row0+128). Split-K (2-way, z) for
// rows >= 2048; both halves atomicAdd into pre-zeroed out (2 addends ->
// commutative -> bit-deterministic).
// ============================================================================
__global__ __launch_bounds__(256) void gemm_pv(
    const u16* __restrict__ P, const u16* __restrict__ vT, float* __restrict__ C)
{
  __shared__ alignas(16) u16 sA[128 * 64];
  __shared__ alignas(16) u16 sB[128 * 64];
  const int row0 = blockIdx.y * 128, col0 = blockIdx.x * 128;
  const int Klim = row0 + 128;
  int klo = 0, khi = Klim;
  bool use_atomic = false;
  if (Klim <= 2048) {
    if (blockIdx.z) return;
  } else {
    use_atomic = true;
    const int Kh = Klim >> 1;  // multiple of 64
    if (blockIdx.z == 0) khi = Kh; else klo = Kh;
  }

  f32x4 acc[4][4] = {};
  mm128(P, vT, NTOK, NTOK, klo, khi, row0, col0, sA, sB, acc);

  const int lane = threadIdx.x & 63;
  const int wave = threadIdx.x >> 6;
  const int l15 = lane & 15, l4 = lane >> 4;
  const int om = row0 + (wave >> 1) * 64;
  const int on = col0 + (wave & 1) * 64;
#pragma unroll
  for (int mf = 0; mf < 4; ++mf)
#pragma unroll
    for (int nf = 0; nf < 4; ++nf)
#pragma unroll
      for (int r = 0; r < 4; ++r) {
        const size_t idx = (size_t)(om + mf * 16 + l4 * 4 + r) * DIM + (on + nf * 16 + l15);
        if (use_atomic) atomicAdd(&C[idx], acc[mf][nf][r]);
        else C[idx] = acc[mf][nf][r];
      }
}

// ---------- causal row softmax: S fp32 -> P bf16, only cols < (row&~127)+128 ----------
__global__ __launch_bounds__(256) void softmax_causal(const float* __restrict__ S,
                                                      u16* __restrict__ P) {
  __shared__ float buf[NTOK];
  __shared__ float red[8];
  const int row = blockIdx.x;
  const int tid = threadIdx.x;
  const int limit = row + 1;
  const int limit128 = (row & ~127) + 128;  // PV reads exactly cols [0, limit128)
  const float* srow = S + (size_t)row * NTOK;

  float lmax = -1e30f;
  for (int j = tid * 4; j < limit128; j += 1024) {
    float4 s;
    if (j + 4 <= limit) {
      s = *reinterpret_cast<const float4*>(srow + j);
    } else {
      s.x = (j + 0 < limit) ? srow[j + 0] : -1e30f;
      s.y = (j + 1 < limit) ? srow[j + 1] : -1e30f;
      s.z = (j + 2 < limit) ? srow[j + 2] : -1e30f;
      s.w = (j + 3 < limit) ? srow[j + 3] : -1e30f;
    }
    *reinterpret_cast<float4*>(buf + j) = s;
    lmax = fmaxf(lmax, fmaxf(fmaxf(s.x, s.y), fmaxf(s.z, s.w)));
  }
  lmax = wave_max(lmax);
  if ((tid & 63) == 0) red[tid >> 6] = lmax;
  __syncthreads();
  const float m = fmaxf(fmaxf(red[0], red[1]), fmaxf(red[2], red[3]));

  float lsum = 0.f;
  for (int j = tid * 4; j < limit128; j += 1024) {
    float4 s = *reinterpret_cast<float4*>(buf + j);
    float4 e;
    e.x = __expf(s.x - m); e.y = __expf(s.y - m);
    e.z = __expf(s.z - m); e.w = __expf(s.w - m);
    *reinterpret_cast<float4*>(buf + j) = e;
    lsum += (e.x + e.y) + (e.z + e.w);
  }
  lsum = wave_sum(lsum);
  if ((tid & 63) == 0) red[4 + (tid >> 6)] = lsum;
  __syncthreads();
  const float inv = 1.0f / (red[4] + red[5] + red[6] + red[7]);

  u16* prow = P + (size_t)row * NTOK;
  for (int j = tid * 4; j < limit128; j += 1024) {
    float4 e = *reinterpret_cast<float4*>(buf + j);
    ushort4 o;
    o.x = f2bf(e.x * inv); o.y = f2bf(e.y * inv);
    o.z = f2bf(e.z * inv); o.w = f2bf(e.w * inv);
    *reinterpret_cast<ushort4*>(prow + j) = o;
  }
}

// ---------- launcher ----------
extern "C" void kernel_launch(void* const* d_in, const int* in_sizes, int n_in,
                              void* d_out, int out_size, void* d_ws, size_t ws_size,
                              hipStream_t stream) {
  const float* qx = (const float*)d_in[0];
  const float* kx = (const float*)d_in[1];
  const float* vx = (const float*)d_in[2];
  const float* Wq = (const float*)d_in[3];
  const float* Wk = (const float*)d_in[4];
  const float* Wv = (const float*)d_in[5];
  float* out = (float*)d_out;
  char* ws = (char*)d_ws;
  const size_t MB = 1024ull * 1024ull;

  if (ws_size < 120 * MB) {
    hipMemsetAsync(d_out, 0xFF, (size_t)out_size * sizeof(float), stream);
    return;
  }

  // ws layout (120 MB):
  //   [0,30)  bf16 cvt buffers (dead after proj_sw)
  //   [0,64)  S fp32 (overlays cvt buffers; written by scores AFTER proj)
  //   [64,72) qb | [72,80) kb | [80,88) vT | [88,120) P
  u16* qxb = (u16*)(ws);
  u16* kxb = (u16*)(ws + 8 * MB);
  u16* vxb = (u16*)(ws + 16 * MB);
  u16* Wqb = (u16*)(ws + 24 * MB);
  u16* Wkb = (u16*)(ws + 26 * MB);
  u16* Wvb = (u16*)(ws + 28 * MB);
  float* S = (float*)(ws);
  u16* qb  = (u16*)(ws + 64 * MB);
  u16* kb  = (u16*)(ws + 72 * MB);
  u16* vT  = (u16*)(ws + 80 * MB);
  u16* P   = (u16*)(ws + 88 * MB);

  // zero rows >= 2048 of out (atomicAdd targets for the split-K PV)
  hipMemsetAsync((char*)out + (size_t)2048 * DIM * 4, 0, (size_t)2048 * DIM * 4, stream);

  // fp32 -> bf16 for all six inputs (memory-bound, ~90MB total)
  cvt6<<<dim3(NTOK * DIM / (256 * 8), 1, 6), 256, 0, stream>>>(
      qx, kx, vx, Wq, Wk, Wv, qxb, kxb, vxb, Wqb, Wkb, Wvb);

  // projections (swizzled gload_lds GEMM), 768 blocks
  proj_sw<<<dim3(DIM / 128, NTOK / 128, 3), 256, 0, stream>>>(
      qxb, kxb, vxb, Wqb, Wkb, Wvb, qb, kb, vT);

  // scores: S = (q @ k^T) / 32, lower-triangular tiles only
  gemm_scores<<<dim3(NTOK / 128, NTOK / 128), 256, 0, stream>>>(qb, kb, S, 0.03125f);

  softmax_causal<<<NTOK, 256, 0, stream>>>(S, P);

  // out = P @ v, causal K-limit, split-K for rows >= 2048
  gemm_pv<<<dim3(DIM / 128, NTOK / 128, 2), 256, 0, stream>>>(P, vT, out);
}

// Round 4
// 144.439 us; speedup vs baseline: 1.4577x; 1.1087x over previous
//
#include <hip/hip_runtime.h>
#include <hip/hip_bf16.h>
#include <stdint.h>

#define NTOK 4096
#define DIM  1024

typedef unsigned short u16;
typedef __bf16 bf16x8 __attribute__((ext_vector_type(8)));
typedef float f32x4 __attribute__((ext_vector_type(4)));
typedef u16 u16x8 __attribute__((ext_vector_type(8)));

// ---------- helpers ----------
__device__ __forceinline__ u16 f2bf(float f) {
  union { float f; uint32_t u; } c; c.f = f;
  return (u16)((c.u + 0x7fffu + ((c.u >> 16) & 1u)) >> 16);  // RNE
}

__device__ __forceinline__ float wave_max(float v) {
#pragma unroll
  for (int o = 32; o; o >>= 1) v = fmaxf(v, __shfl_xor(v, o, 64));
  return v;
}
__device__ __forceinline__ float wave_sum(float v) {
#pragma unroll
  for (int o = 32; o; o >>= 1) v += __shfl_xor(v, o, 64);
  return v;
}

// bijective XCD swizzle (m204): original dispatch id -> logical work id so that
// each XCD (= orig%8) processes a CONTIGUOUS chunk of logical ids (L2 locality).
__device__ __forceinline__ int xcd_swz(int orig, int nwg) {
  const int q = nwg >> 3, r = nwg & 7;
  const int x = orig & 7, i = orig >> 3;
  return (x < r ? x * (q + 1) : r * (q + 1) + (x - r) * q) + i;
}

// async global->LDS, 16B per lane. LDS dest must be wave-uniform base (HW adds lane*16).
__device__ __forceinline__ void gld16(const u16* g, u16* l) {
  __builtin_amdgcn_global_load_lds((const __attribute__((address_space(1))) void*)g,
                                   (__attribute__((address_space(3))) void*)l, 16, 0, 0);
}

// ============================================================================
// fp32 -> bf16 conversion, 8 elems/thread. z selects tensor.
// ============================================================================
__global__ __launch_bounds__(256) void cvt6(
    const float* __restrict__ qx, const float* __restrict__ kx, const float* __restrict__ vx,
    const float* __restrict__ Wq, const float* __restrict__ Wk, const float* __restrict__ Wv,
    u16* __restrict__ qxb, u16* __restrict__ kxb, u16* __restrict__ vxb,
    u16* __restrict__ Wqb, u16* __restrict__ Wkb, u16* __restrict__ Wvb)
{
  const int z = blockIdx.z;
  const int nelem = (z < 3) ? NTOK * DIM : DIM * DIM;
  const int i = (blockIdx.x * 256 + threadIdx.x) * 8;
  if (i >= nelem) return;
  const float* in = (z == 0) ? qx : (z == 1) ? kx : (z == 2) ? vx
                  : (z == 3) ? Wq : (z == 4) ? Wk : Wv;
  u16* out = (z == 0) ? qxb : (z == 1) ? kxb : (z == 2) ? vxb
           : (z == 3) ? Wqb : (z == 4) ? Wkb : Wvb;
  float4 a = *reinterpret_cast<const float4*>(in + i);
  float4 b = *reinterpret_cast<const float4*>(in + i + 4);
  u16x8 o;
  o[0] = f2bf(a.x); o[1] = f2bf(a.y); o[2] = f2bf(a.z); o[3] = f2bf(a.w);
  o[4] = f2bf(b.x); o[5] = f2bf(b.y); o[6] = f2bf(b.z); o[7] = f2bf(b.w);
  *reinterpret_cast<u16x8*>(out + i) = o;
}

// ============================================================================
// BMx128xK core: C_tile += A @ B^T (A:[*,lda], B:[*,ldb] bf16). BM in {64,128}.
// global_load_lds(16B) staging, linear LDS dest, pre-swizzled global source
// (chunk = (lane&7)^(lane>>3)), XOR-swizzled ds_read -> conflict-free (verified R3).
// 4 waves: wave output = (BM/2)x64 sub-tile at (wave>>1, wave&1).
// ============================================================================
template<int BM>
__device__ __forceinline__ void mm_core(
    const u16* __restrict__ A, const u16* __restrict__ B,
    int lda, int ldb, int klo, int khi, int row0, int col0,
    u16* sA, u16* sB, f32x4 (&acc)[BM / 32][4])
{
  constexpr int RPWA = BM / 4;  // A rows staged per wave
  const int tid = threadIdx.x;
  const int wave = tid >> 6, lane = tid & 63;
  const int wr = wave >> 1, wc = wave & 1;
  const int l15 = lane & 15, l4 = lane >> 4;
  const int h = l15 & 7;

  const int r8 = lane >> 3;
  const int scol = ((lane & 7) ^ r8) << 3;
  const u16* gA = A + (size_t)(row0 + wave * RPWA + r8) * lda + scol;
  const u16* gB = B + (size_t)(col0 + wave * 32 + r8) * ldb + scol;
  const int lbA = wave * RPWA * 64;
  const int lbB = wave * 32 * 64;

  for (int k0 = klo; k0 < khi; k0 += 64) {
    __syncthreads();
#pragma unroll
    for (int i = 0; i < RPWA / 8; ++i)
      gld16(gA + (size_t)(i * 8) * lda + k0, &sA[lbA + i * 8 * 64]);
#pragma unroll
    for (int i = 0; i < 4; ++i)
      gld16(gB + (size_t)(i * 8) * ldb + k0, &sB[lbB + i * 8 * 64]);
    __syncthreads();  // compiler drains vmcnt(0) before barrier -> LDS ready
#pragma unroll
    for (int ks = 0; ks < 2; ++ks) {
      bf16x8 af[BM / 32], bfv[4];
#pragma unroll
      for (int mf = 0; mf < BM / 32; ++mf)
        af[mf] = *reinterpret_cast<const bf16x8*>(
            (const char*)sA + ((wr * (BM / 2) + mf * 16 + l15) << 7) + ((((ks << 2) + l4) ^ h) << 4));
#pragma unroll
      for (int nf = 0; nf < 4; ++nf)
        bfv[nf] = *reinterpret_cast<const bf16x8*>(
            (const char*)sB + ((wc * 64 + nf * 16 + l15) << 7) + ((((ks << 2) + l4) ^ h) << 4));
#pragma unroll
      for (int mf = 0; mf < BM / 32; ++mf)
#pragma unroll
        for (int nf = 0; nf < 4; ++nf)
          acc[mf][nf] = __builtin_amdgcn_mfma_f32_16x16x32_bf16(af[mf], bfv[nf], acc[mf][nf], 0, 0, 0);
    }
  }
}

// ============================================================================
// Projections: y = x @ W^T, bf16 in/out. 1-D grid 768 = 3 tensors x (32 by x 8 bx),
// XCD-swizzled. z=2 stores v transposed [DIM,NTOK] for the PV B-operand.
// ============================================================================
__global__ __launch_bounds__(256) void proj_sw(
    const u16* __restrict__ qxb, const u16* __restrict__ kxb, const u16* __restrict__ vxb,
    const u16* __restrict__ Wqb, const u16* __restrict__ Wkb, const u16* __restrict__ Wvb,
    u16* __restrict__ qb, u16* __restrict__ kb, u16* __restrict__ vT)
{
  __shared__ alignas(16) u16 sA[128 * 64];
  __shared__ alignas(16) u16 sB[128 * 64];
  const int w = xcd_swz(blockIdx.x, 768);
  const int z = w >> 8, rem = w & 255;
  const int by = rem >> 3, bx = rem & 7;
  const u16* A = (z == 0) ? qxb : (z == 1) ? kxb : vxb;
  const u16* B = (z == 0) ? Wqb : (z == 1) ? Wkb : Wvb;
  const int row0 = by * 128, col0 = bx * 128;

  f32x4 acc[4][4] = {};
  mm_core<128>(A, B, DIM, DIM, 0, DIM, row0, col0, sA, sB, acc);

  const int lane = threadIdx.x & 63;
  const int wave = threadIdx.x >> 6;
  const int l15 = lane & 15, l4 = lane >> 4;
  const int om = row0 + (wave >> 1) * 64;
  const int on = col0 + (wave & 1) * 64;
  if (z < 2) {
    u16* C = (z == 0) ? qb : kb;
#pragma unroll
    for (int mf = 0; mf < 4; ++mf)
#pragma unroll
      for (int nf = 0; nf < 4; ++nf)
#pragma unroll
        for (int r = 0; r < 4; ++r)
          C[(size_t)(om + mf * 16 + l4 * 4 + r) * DIM + (on + nf * 16 + l15)] = f2bf(acc[mf][nf][r]);
  } else {  // v transposed: 4 consecutive rows -> contiguous 8B store
#pragma unroll
    for (int mf = 0; mf < 4; ++mf)
#pragma unroll
      for (int nf = 0; nf < 4; ++nf) {
        ushort4 o;
        o.x = f2bf(acc[mf][nf][0]);
        o.y = f2bf(acc[mf][nf][1]);
        o.z = f2bf(acc[mf][nf][2]);
        o.w = f2bf(acc[mf][nf][3]);
        *reinterpret_cast<ushort4*>(&vT[(size_t)(on + nf * 16 + l15) * NTOK + (om + mf * 16 + l4 * 4)]) = o;
      }
  }
}

// ============================================================================
// Scores: S = (q @ k^T) * scale. 1-D grid of exactly 528 lower-triangle tiles,
// XCD-swizzled; t -> (by, bx) via triangular-number decode.
// ============================================================================
__global__ __launch_bounds__(256) void gemm_scores(
    const u16* __restrict__ A, const u16* __restrict__ B, float* __restrict__ C, float scale)
{
  __shared__ alignas(16) u16 sA[128 * 64];
  __shared__ alignas(16) u16 sB[128 * 64];
  const int t = xcd_swz(blockIdx.x, 528);
  int by = (int)((sqrtf(8.0f * t + 1.0f) - 1.0f) * 0.5f);
  while ((by + 1) * (by + 2) / 2 <= t) ++by;
  while (by * (by + 1) / 2 > t) --by;
  const int bx = t - by * (by + 1) / 2;
  const int row0 = by * 128, col0 = bx * 128;

  f32x4 acc[4][4] = {};
  mm_core<128>(A, B, DIM, DIM, 0, DIM, row0, col0, sA, sB, acc);

  const int lane = threadIdx.x & 63;
  const int wave = threadIdx.x >> 6;
  const int l15 = lane & 15, l4 = lane >> 4;
  const int om = row0 + (wave >> 1) * 64;
  const int on = col0 + (wave & 1) * 64;
#pragma unroll
  for (int mf = 0; mf < 4; ++mf)
#pragma unroll
    for (int nf = 0; nf < 4; ++nf)
#pragma unroll
      for (int r = 0; r < 4; ++r)
        C[(size_t)(om + mf * 16 + l4 * 4 + r) * NTOK + (on + nf * 16 + l15)] = acc[mf][nf][r] * scale;
}

// ============================================================================
// PV: out = P @ vT^T. 64x128 tiles: 1-D grid 768 = 96 chunks x 8 bx (bx inner).
// by<32: single chunk (K = row0+64). by>=32: 2-way split-K, halves rounded to
// 64; both atomicAdd into pre-zeroed out (2 addends -> commutative -> determ.)
// ============================================================================
__global__ __launch_bounds__(256) void gemm_pv(
    const u16* __restrict__ P, const u16* __restrict__ vT, float* __restrict__ C)
{
  __shared__ alignas(16) u16 sA[64 * 64];
  __shared__ alignas(16) u16 sB[128 * 64];
  const int w = xcd_swz(blockIdx.x, 768);
  const int bx = w & 7;
  const int cid = w >> 3;  // 0..95
  int by, half;
  if (cid < 32) { by = cid; half = -1; }
  else { const int j = cid - 32; by = 32 + (j >> 1); half = j & 1; }
  const int row0 = by * 64, col0 = bx * 128;
  const int Klim = row0 + 64;
  int klo = 0, khi = Klim;
  if (half >= 0) {
    const int h1 = (((Klim >> 6) + 1) >> 1) << 6;  // ceil(nsteps/2)*64
    if (half == 0) khi = h1; else klo = h1;
  }

  f32x4 acc[2][4] = {};
  mm_core<64>(P, vT, NTOK, NTOK, klo, khi, row0, col0, sA, sB, acc);

  const int lane = threadIdx.x & 63;
  const int wave = threadIdx.x >> 6;
  const int l15 = lane & 15, l4 = lane >> 4;
  const int om = row0 + (wave >> 1) * 32;
  const int on = col0 + (wave & 1) * 64;
#pragma unroll
  for (int mf = 0; mf < 2; ++mf)
#pragma unroll
    for (int nf = 0; nf < 4; ++nf)
#pragma unroll
      for (int r = 0; r < 4; ++r) {
        const size_t idx = (size_t)(om + mf * 16 + l4 * 4 + r) * DIM + (on + nf * 16 + l15);
        if (half >= 0) atomicAdd(&C[idx], acc[mf][nf][r]);
        else C[idx] = acc[mf][nf][r];
      }
}

// ---------- causal row softmax: S fp32 -> P bf16, only cols < (row&~127)+128 ----------
__global__ __launch_bounds__(256) void softmax_causal(const float* __restrict__ S,
                                                      u16* __restrict__ P) {
  __shared__ float buf[NTOK];
  __shared__ float red[8];
  const int row = blockIdx.x;
  const int tid = threadIdx.x;
  const int limit = row + 1;
  const int limit128 = (row & ~127) + 128;  // PV reads exactly cols [0, limit128)
  const float* srow = S + (size_t)row * NTOK;

  float lmax = -1e30f;
  for (int j = tid * 4; j < limit128; j += 1024) {
    float4 s;
    if (j + 4 <= limit) {
      s = *reinterpret_cast<const float4*>(srow + j);
    } else {
      s.x = (j + 0 < limit) ? srow[j + 0] : -1e30f;
      s.y = (j + 1 < limit) ? srow[j + 1] : -1e30f;
      s.z = (j + 2 < limit) ? srow[j + 2] : -1e30f;
      s.w = (j + 3 < limit) ? srow[j + 3] : -1e30f;
    }
    *reinterpret_cast<float4*>(buf + j) = s;
    lmax = fmaxf(lmax, fmaxf(fmaxf(s.x, s.y), fmaxf(s.z, s.w)));
  }
  lmax = wave_max(lmax);
  if ((tid & 63) == 0) red[tid >> 6] = lmax;
  __syncthreads();
  const float m = fmaxf(fmaxf(red[0], red[1]), fmaxf(red[2], red[3]));

  float lsum = 0.f;
  for (int j = tid * 4; j < limit128; j += 1024) {
    float4 s = *reinterpret_cast<float4*>(buf + j);
    float4 e;
    e.x = __expf(s.x - m); e.y = __expf(s.y - m);
    e.z = __expf(s.z - m); e.w = __expf(s.w - m);
    *reinterpret_cast<float4*>(buf + j) = e;
    lsum += (e.x + e.y) + (e.z + e.w);
  }
  lsum = wave_sum(lsum);
  if ((tid & 63) == 0) red[4 + (tid >> 6)] = lsum;
  __syncthreads();
  const float inv = 1.0f / (red[4] + red[5] + red[6] + red[7]);

  u16* prow = P + (size_t)row * NTOK;
  for (int j = tid * 4; j < limit128; j += 1024) {
    float4 e = *reinterpret_cast<float4*>(buf + j);
    ushort4 o;
    o.x = f2bf(e.x * inv); o.y = f2bf(e.y * inv);
    o.z = f2bf(e.z * inv); o.w = f2bf(e.w * inv);
    *reinterpret_cast<ushort4*>(prow + j) = o;
  }
}

// ---------- launcher ----------
extern "C" void kernel_launch(void* const* d_in, const int* in_sizes, int n_in,
                              void* d_out, int out_size, void* d_ws, size_t ws_size,
                              hipStream_t stream) {
  const float* qx = (const float*)d_in[0];
  const float* kx = (const float*)d_in[1];
  const float* vx = (const float*)d_in[2];
  const float* Wq = (const float*)d_in[3];
  const float* Wk = (const float*)d_in[4];
  const float* Wv = (const float*)d_in[5];
  float* out = (float*)d_out;
  char* ws = (char*)d_ws;
  const size_t MB = 1024ull * 1024ull;

  if (ws_size < 120 * MB) {
    hipMemsetAsync(d_out, 0xFF, (size_t)out_size * sizeof(float), stream);
    return;
  }

  // ws layout (120 MB):
  //   [0,30)  bf16 cvt buffers (dead after proj_sw)
  //   [0,64)  S fp32 (overlays cvt buffers; written by scores AFTER proj)
  //   [64,72) qb | [72,80) kb | [80,88) vT | [88,120) P
  u16* qxb = (u16*)(ws);
  u16* kxb = (u16*)(ws + 8 * MB);
  u16* vxb = (u16*)(ws + 16 * MB);
  u16* Wqb = (u16*)(ws + 24 * MB);
  u16* Wkb = (u16*)(ws + 26 * MB);
  u16* Wvb = (u16*)(ws + 28 * MB);
  float* S = (float*)(ws);
  u16* qb  = (u16*)(ws + 64 * MB);
  u16* kb  = (u16*)(ws + 72 * MB);
  u16* vT  = (u16*)(ws + 80 * MB);
  u16* P   = (u16*)(ws + 88 * MB);

  // zero rows >= 2048 of out (atomicAdd targets for the split-K PV)
  hipMemsetAsync((char*)out + (size_t)2048 * DIM * 4, 0, (size_t)2048 * DIM * 4, stream);

  // fp32 -> bf16 for all six inputs (memory-bound, ~90MB total)
  cvt6<<<dim3(NTOK * DIM / (256 * 8), 1, 6), 256, 0, stream>>>(
      qx, kx, vx, Wq, Wk, Wv, qxb, kxb, vxb, Wqb, Wkb, Wvb);

  // projections (swizzled gload_lds GEMM, XCD-chunked), 768 blocks
  proj_sw<<<768, 256, 0, stream>>>(qxb, kxb, vxb, Wqb, Wkb, Wvb, qb, kb, vT);

  // scores: S = (q @ k^T) / 32, exactly the 528 lower-triangle tiles
  gemm_scores<<<528, 256, 0, stream>>>(qb, kb, S, 0.03125f);

  softmax_causal<<<NTOK, 256, 0, stream>>>(S, P);

  // out = P @ v: 64-row tiles, causal K-limit, split-K for rows >= 2048
  gemm_pv<<<768, 256, 0, stream>>>(P, vT, out);
}

// Round 5
// 140.512 us; speedup vs baseline: 1.4984x; 1.0280x over previous
//
#include <hip/hip_runtime.h>
#include <hip/hip_bf16.h>
#include <stdint.h>

#define NTOK 4096
#define DIM  1024

typedef unsigned short u16;
typedef __bf16 bf16x8 __attribute__((ext_vector_type(8)));
typedef float f32x4 __attribute__((ext_vector_type(4)));
typedef u16 u16x8 __attribute__((ext_vector_type(8)));

// ---------- helpers ----------
__device__ __forceinline__ u16 f2bf(float f) {
  union { float f; uint32_t u; } c; c.f = f;
  return (u16)((c.u + 0x7fffu + ((c.u >> 16) & 1u)) >> 16);  // RNE
}
__device__ __forceinline__ float bf2f(u16 b) {
  union { uint32_t u; float f; } c; c.u = (uint32_t)b << 16;
  return c.f;
}

__device__ __forceinline__ float wave_max(float v) {
#pragma unroll
  for (int o = 32; o; o >>= 1) v = fmaxf(v, __shfl_xor(v, o, 64));
  return v;
}
__device__ __forceinline__ float wave_sum(float v) {
#pragma unroll
  for (int o = 32; o; o >>= 1) v += __shfl_xor(v, o, 64);
  return v;
}

// bijective XCD swizzle (m204): orig dispatch id -> logical work id; each XCD
// (= orig%8) gets a contiguous chunk of logical ids (L2 locality).
__device__ __forceinline__ int xcd_swz(int orig, int nwg) {
  const int q = nwg >> 3, r = nwg & 7;
  const int x = orig & 7, i = orig >> 3;
  return (x < r ? x * (q + 1) : r * (q + 1) + (x - r) * q) + i;
}

// async global->LDS, 16B per lane. LDS dest wave-uniform base (HW adds lane*16).
__device__ __forceinline__ void gld16(const u16* g, u16* l) {
  __builtin_amdgcn_global_load_lds((const __attribute__((address_space(1))) void*)g,
                                   (__attribute__((address_space(3))) void*)l, 16, 0, 0);
}

// ============================================================================
// fp32 -> bf16 conversion, 8 elems/thread. z selects tensor.
// ============================================================================
__global__ __launch_bounds__(256) void cvt6(
    const float* __restrict__ qx, const float* __restrict__ kx, const float* __restrict__ vx,
    const float* __restrict__ Wq, const float* __restrict__ Wk, const float* __restrict__ Wv,
    u16* __restrict__ qxb, u16* __restrict__ kxb, u16* __restrict__ vxb,
    u16* __restrict__ Wqb, u16* __restrict__ Wkb, u16* __restrict__ Wvb)
{
  const int z = blockIdx.z;
  const int nelem = (z < 3) ? NTOK * DIM : DIM * DIM;
  const int i = (blockIdx.x * 256 + threadIdx.x) * 8;
  if (i >= nelem) return;
  const float* in = (z == 0) ? qx : (z == 1) ? kx : (z == 2) ? vx
                  : (z == 3) ? Wq : (z == 4) ? Wk : Wv;
  u16* out = (z == 0) ? qxb : (z == 1) ? kxb : (z == 2) ? vxb
           : (z == 3) ? Wqb : (z == 4) ? Wkb : Wvb;
  float4 a = *reinterpret_cast<const float4*>(in + i);
  float4 b = *reinterpret_cast<const float4*>(in + i + 4);
  u16x8 o;
  o[0] = f2bf(a.x); o[1] = f2bf(a.y); o[2] = f2bf(a.z); o[3] = f2bf(a.w);
  o[4] = f2bf(b.x); o[5] = f2bf(b.y); o[6] = f2bf(b.z); o[7] = f2bf(b.w);
  *reinterpret_cast<u16x8*>(out + i) = o;
}

// ============================================================================
// BMx128xK core, DOUBLE-BUFFERED (T3-minimum 2-phase): STAGE(t+1) is issued
// into buf^1 BEFORE compute(buf); the single __syncthreads() per K-step
// (compiler drains vmcnt(0)+lgkmcnt(0)) lands AFTER compute, so global-load
// latency hides under the MFMA+ds_read of the current tile.
// global_load_lds(16B), linear LDS dest, pre-swizzled global source
// (chunk = (lane&7)^(lane>>3)), XOR-swizzled ds_read -> conflict-free (R3/R4: 0).
// sA: [2][BM*64], sB: [2][128*64]. 4 waves, wave = (BM/2)x64 output sub-tile.
// ============================================================================
template<int BM>
__device__ __forceinline__ void mm_core(
    const u16* __restrict__ A, const u16* __restrict__ B,
    int lda, int ldb, int klo, int khi, int row0, int col0,
    u16* sA, u16* sB, f32x4 (&acc)[BM / 32][4])
{
  constexpr int RPWA = BM / 4;       // A rows staged per wave
  constexpr int ASZ = BM * 64;       // elems per A buffer
  constexpr int BSZ = 128 * 64;      // elems per B buffer
  const int tid = threadIdx.x;
  const int wave = tid >> 6, lane = tid & 63;
  const int wr = wave >> 1, wc = wave & 1;
  const int l15 = lane & 15, l4 = lane >> 4;
  const int h = l15 & 7;

  const int r8 = lane >> 3;
  const int scol = ((lane & 7) ^ r8) << 3;
  const u16* gA = A + (size_t)(row0 + wave * RPWA + r8) * lda + scol;
  const u16* gB = B + (size_t)(col0 + wave * 32 + r8) * ldb + scol;
  const int lbA = wave * RPWA * 64;
  const int lbB = wave * 32 * 64;

  // prologue: stage tile(klo) into buffer 0
#pragma unroll
  for (int i = 0; i < RPWA / 8; ++i)
    gld16(gA + (size_t)(i * 8) * lda + klo, &sA[lbA + i * 512]);
#pragma unroll
  for (int i = 0; i < 4; ++i)
    gld16(gB + (size_t)(i * 8) * ldb + klo, &sB[lbB + i * 512]);
  __syncthreads();

  int cur = 0;
  for (int k0 = klo; k0 < khi; k0 += 64) {
    const int nxt = cur ^ 1;
    if (k0 + 64 < khi) {  // prefetch next K-tile into the other buffer (async)
#pragma unroll
      for (int i = 0; i < RPWA / 8; ++i)
        gld16(gA + (size_t)(i * 8) * lda + k0 + 64, &sA[nxt * ASZ + lbA + i * 512]);
#pragma unroll
      for (int i = 0; i < 4; ++i)
        gld16(gB + (size_t)(i * 8) * ldb + k0 + 64, &sB[nxt * BSZ + lbB + i * 512]);
    }
    const char* bA = (const char*)(sA + cur * ASZ);
    const char* bB = (const char*)(sB + cur * BSZ);
#pragma unroll
    for (int ks = 0; ks < 2; ++ks) {
      bf16x8 af[BM / 32], bfv[4];
#pragma unroll
      for (int mf = 0; mf < BM / 32; ++mf)
        af[mf] = *reinterpret_cast<const bf16x8*>(
            bA + ((wr * (BM / 2) + mf * 16 + l15) << 7) + ((((ks << 2) + l4) ^ h) << 4));
#pragma unroll
      for (int nf = 0; nf < 4; ++nf)
        bfv[nf] = *reinterpret_cast<const bf16x8*>(
            bB + ((wc * 64 + nf * 16 + l15) << 7) + ((((ks << 2) + l4) ^ h) << 4));
#pragma unroll
      for (int mf = 0; mf < BM / 32; ++mf)
#pragma unroll
        for (int nf = 0; nf < 4; ++nf)
          acc[mf][nf] = __builtin_amdgcn_mfma_f32_16x16x32_bf16(af[mf], bfv[nf], acc[mf][nf], 0, 0, 0);
    }
    __syncthreads();  // drains prefetch vmcnt + ds_reads; buffers swap safely
    cur = nxt;
  }
}

// ============================================================================
// Projections: y = x @ W^T, bf16 in/out. 1-D grid 768 = 3 tensors x (32 by x 8 bx),
// XCD-swizzled. z=2 stores v transposed [DIM,NTOK] for the PV B-operand.
// ============================================================================
__global__ __launch_bounds__(256) void proj_sw(
    const u16* __restrict__ qxb, const u16* __restrict__ kxb, const u16* __restrict__ vxb,
    const u16* __restrict__ Wqb, const u16* __restrict__ Wkb, const u16* __restrict__ Wvb,
    u16* __restrict__ qb, u16* __restrict__ kb, u16* __restrict__ vT)
{
  __shared__ alignas(16) u16 sA[2 * 128 * 64];
  __shared__ alignas(16) u16 sB[2 * 128 * 64];
  const int w = xcd_swz(blockIdx.x, 768);
  const int z = w >> 8, rem = w & 255;
  const int by = rem >> 3, bx = rem & 7;
  const u16* A = (z == 0) ? qxb : (z == 1) ? kxb : vxb;
  const u16* B = (z == 0) ? Wqb : (z == 1) ? Wkb : Wvb;
  const int row0 = by * 128, col0 = bx * 128;

  f32x4 acc[4][4] = {};
  mm_core<128>(A, B, DIM, DIM, 0, DIM, row0, col0, sA, sB, acc);

  const int lane = threadIdx.x & 63;
  const int wave = threadIdx.x >> 6;
  const int l15 = lane & 15, l4 = lane >> 4;
  const int om = row0 + (wave >> 1) * 64;
  const int on = col0 + (wave & 1) * 64;
  if (z < 2) {
    u16* C = (z == 0) ? qb : kb;
#pragma unroll
    for (int mf = 0; mf < 4; ++mf)
#pragma unroll
      for (int nf = 0; nf < 4; ++nf)
#pragma unroll
        for (int r = 0; r < 4; ++r)
          C[(size_t)(om + mf * 16 + l4 * 4 + r) * DIM + (on + nf * 16 + l15)] = f2bf(acc[mf][nf][r]);
  } else {  // v transposed: 4 consecutive rows -> contiguous 8B store
#pragma unroll
    for (int mf = 0; mf < 4; ++mf)
#pragma unroll
      for (int nf = 0; nf < 4; ++nf) {
        ushort4 o;
        o.x = f2bf(acc[mf][nf][0]);
        o.y = f2bf(acc[mf][nf][1]);
        o.z = f2bf(acc[mf][nf][2]);
        o.w = f2bf(acc[mf][nf][3]);
        *reinterpret_cast<ushort4*>(&vT[(size_t)(on + nf * 16 + l15) * NTOK + (om + mf * 16 + l4 * 4)]) = o;
      }
  }
}

// ============================================================================
// Scores: S = (q @ k^T) * scale, bf16 out (halves S traffic; score std ~1 ->
// bf16 rounding ~0.4% of range, well inside tolerance). 528 triangle tiles.
// ============================================================================
__global__ __launch_bounds__(256) void gemm_scores(
    const u16* __restrict__ A, const u16* __restrict__ B, u16* __restrict__ C, float scale)
{
  __shared__ alignas(16) u16 sA[2 * 128 * 64];
  __shared__ alignas(16) u16 sB[2 * 128 * 64];
  const int t = xcd_swz(blockIdx.x, 528);
  int by = (int)((sqrtf(8.0f * t + 1.0f) - 1.0f) * 0.5f);
  while ((by + 1) * (by + 2) / 2 <= t) ++by;
  while (by * (by + 1) / 2 > t) --by;
  const int bx = t - by * (by + 1) / 2;
  const int row0 = by * 128, col0 = bx * 128;

  f32x4 acc[4][4] = {};
  mm_core<128>(A, B, DIM, DIM, 0, DIM, row0, col0, sA, sB, acc);

  const int lane = threadIdx.x & 63;
  const int wave = threadIdx.x >> 6;
  const int l15 = lane & 15, l4 = lane >> 4;
  const int om = row0 + (wave >> 1) * 64;
  const int on = col0 + (wave & 1) * 64;
#pragma unroll
  for (int mf = 0; mf < 4; ++mf)
#pragma unroll
    for (int nf = 0; nf < 4; ++nf)
#pragma unroll
      for (int r = 0; r < 4; ++r)
        C[(size_t)(om + mf * 16 + l4 * 4 + r) * NTOK + (on + nf * 16 + l15)] = f2bf(acc[mf][nf][r] * scale);
}

// ============================================================================
// PV: out = P @ vT^T. 64x128 tiles: 1-D grid 768 = 96 chunks x 8 bx.
// by<32: single chunk (K = row0+64). by>=32: 2-way split-K; both halves
// atomicAdd into pre-zeroed out.
// ============================================================================
__global__ __launch_bounds__(256) void gemm_pv(
    const u16* __restrict__ P, const u16* __restrict__ vT, float* __restrict__ C)
{
  __shared__ alignas(16) u16 sA[2 * 64 * 64];
  __shared__ alignas(16) u16 sB[2 * 128 * 64];
  const int w = xcd_swz(blockIdx.x, 768);
  const int bx = w & 7;
  const int cid = w >> 3;  // 0..95
  int by, half;
  if (cid < 32) { by = cid; half = -1; }
  else { const int j = cid - 32; by = 32 + (j >> 1); half = j & 1; }
  const int row0 = by * 64, col0 = bx * 128;
  const int Klim = row0 + 64;
  int klo = 0, khi = Klim;
  if (half >= 0) {
    const int h1 = (((Klim >> 6) + 1) >> 1) << 6;  // ceil(nsteps/2)*64
    if (half == 0) khi = h1; else klo = h1;
  }

  f32x4 acc[2][4] = {};
  mm_core<64>(P, vT, NTOK, NTOK, klo, khi, row0, col0, sA, sB, acc);

  const int lane = threadIdx.x & 63;
  const int wave = threadIdx.x >> 6;
  const int l15 = lane & 15, l4 = lane >> 4;
  const int om = row0 + (wave >> 1) * 32;
  const int on = col0 + (wave & 1) * 64;
#pragma unroll
  for (int mf = 0; mf < 2; ++mf)
#pragma unroll
    for (int nf = 0; nf < 4; ++nf)
#pragma unroll
      for (int r = 0; r < 4; ++r) {
        const size_t idx = (size_t)(om + mf * 16 + l4 * 4 + r) * DIM + (on + nf * 16 + l15);
        if (half >= 0) atomicAdd(&C[idx], acc[mf][nf][r]);
        else C[idx] = acc[mf][nf][r];
      }
}

// ---------- causal row softmax: S bf16 -> P bf16, cols < (row&~127)+128 ----------
__global__ __launch_bounds__(256) void softmax_causal(const u16* __restrict__ S,
                                                      u16* __restrict__ P) {
  __shared__ float buf[NTOK];
  __shared__ float red[8];
  const int row = blockIdx.x;
  const int tid = threadIdx.x;
  const int limit = row + 1;
  const int limit128 = (row & ~127) + 128;  // PV reads exactly cols [0, limit128)
  const u16* srow = S + (size_t)row * NTOK;

  float lmax = -1e30f;
  for (int j = tid * 8; j < limit128; j += 2048) {
    float v[8];
    if (j + 8 <= limit) {
      u16x8 sv = *reinterpret_cast<const u16x8*>(srow + j);
#pragma unroll
      for (int e = 0; e < 8; ++e) v[e] = bf2f(sv[e]);
    } else {
#pragma unroll
      for (int e = 0; e < 8; ++e) v[e] = (j + e < limit) ? bf2f(srow[j + e]) : -1e30f;
    }
    float4 lo = {v[0], v[1], v[2], v[3]}, hi = {v[4], v[5], v[6], v[7]};
    *reinterpret_cast<float4*>(buf + j) = lo;
    *reinterpret_cast<float4*>(buf + j + 4) = hi;
#pragma unroll
    for (int e = 0; e < 8; ++e) lmax = fmaxf(lmax, v[e]);
  }
  lmax = wave_max(lmax);
  if ((tid & 63) == 0) red[tid >> 6] = lmax;
  __syncthreads();
  const float m = fmaxf(fmaxf(red[0], red[1]), fmaxf(red[2], red[3]));

  float lsum = 0.f;
  for (int j = tid * 8; j < limit128; j += 2048) {
    float4 lo = *reinterpret_cast<float4*>(buf + j);
    float4 hi = *reinterpret_cast<float4*>(buf + j + 4);
    float e0 = __expf(lo.x - m), e1 = __expf(lo.y - m), e2 = __expf(lo.z - m), e3 = __expf(lo.w - m);
    float e4 = __expf(hi.x - m), e5 = __expf(hi.y - m), e6 = __expf(hi.z - m), e7 = __expf(hi.w - m);
    float4 eo = {e0, e1, e2, e3}, eh = {e4, e5, e6, e7};
    *reinterpret_cast<float4*>(buf + j) = eo;
    *reinterpret_cast<float4*>(buf + j + 4) = eh;
    lsum += ((e0 + e1) + (e2 + e3)) + ((e4 + e5) + (e6 + e7));
  }
  lsum = wave_sum(lsum);
  if ((tid & 63) == 0) red[4 + (tid >> 6)] = lsum;
  __syncthreads();
  const float inv = 1.0f / (red[4] + red[5] + red[6] + red[7]);

  u16* prow = P + (size_t)row * NTOK;
  for (int j = tid * 8; j < limit128; j += 2048) {
    float4 lo = *reinterpret_cast<float4*>(buf + j);
    float4 hi = *reinterpret_cast<float4*>(buf + j + 4);
    u16x8 o;
    o[0] = f2bf(lo.x * inv); o[1] = f2bf(lo.y * inv);
    o[2] = f2bf(lo.z * inv); o[3] = f2bf(lo.w * inv);
    o[4] = f2bf(hi.x * inv); o[5] = f2bf(hi.y * inv);
    o[6] = f2bf(hi.z * inv); o[7] = f2bf(hi.w * inv);
    *reinterpret_cast<u16x8*>(prow + j) = o;
  }
}

// ---------- launcher ----------
extern "C" void kernel_launch(void* const* d_in, const int* in_sizes, int n_in,
                              void* d_out, int out_size, void* d_ws, size_t ws_size,
                              hipStream_t stream) {
  const float* qx = (const float*)d_in[0];
  const float* kx = (const float*)d_in[1];
  const float* vx = (const float*)d_in[2];
  const float* Wq = (const float*)d_in[3];
  const float* Wk = (const float*)d_in[4];
  const float* Wv = (const float*)d_in[5];
  float* out = (float*)d_out;
  char* ws = (char*)d_ws;
  const size_t MB = 1024ull * 1024ull;

  if (ws_size < 120 * MB) {
    hipMemsetAsync(d_out, 0xFF, (size_t)out_size * sizeof(float), stream);
    return;
  }

  // ws layout (120 MB):
  //   [0,30)  bf16 cvt buffers (dead after proj_sw)
  //   [0,32)  S bf16 [NTOK,NTOK] (overlays cvt buffers; written after proj)
  //   [64,72) qb | [72,80) kb | [80,88) vT | [88,120) P
  u16* qxb = (u16*)(ws);
  u16* kxb = (u16*)(ws + 8 * MB);
  u16* vxb = (u16*)(ws + 16 * MB);
  u16* Wqb = (u16*)(ws + 24 * MB);
  u16* Wkb = (u16*)(ws + 26 * MB);
  u16* Wvb = (u16*)(ws + 28 * MB);
  u16* S   = (u16*)(ws);
  u16* qb  = (u16*)(ws + 64 * MB);
  u16* kb  = (u16*)(ws + 72 * MB);
  u16* vT  = (u16*)(ws + 80 * MB);
  u16* P   = (u16*)(ws + 88 * MB);

  // zero rows >= 2048 of out (atomicAdd targets for the split-K PV)
  hipMemsetAsync((char*)out + (size_t)2048 * DIM * 4, 0, (size_t)2048 * DIM * 4, stream);

  // fp32 -> bf16 for all six inputs (memory-bound, ~90MB total)
  cvt6<<<dim3(NTOK * DIM / (256 * 8), 1, 6), 256, 0, stream>>>(
      qx, kx, vx, Wq, Wk, Wv, qxb, kxb, vxb, Wqb, Wkb, Wvb);

  // projections (dbuf-prefetch gload_lds GEMM, XCD-chunked), 768 blocks
  proj_sw<<<768, 256, 0, stream>>>(qxb, kxb, vxb, Wqb, Wkb, Wvb, qb, kb, vT);

  // scores: S = (q @ k^T) / 32, exactly the 528 lower-triangle tiles, bf16 out
  gemm_scores<<<528, 256, 0, stream>>>(qb, kb, S, 0.03125f);

  softmax_causal<<<NTOK, 256, 0, stream>>>(S, P);

  // out = P @ v: 64-row tiles, causal K-limit, split-K for rows >= 2048
  gemm_pv<<<768, 256, 0, stream>>>(P, vT, out);
}